// Round 13
// baseline (582.496 us; speedup 1.0000x reference)
//
#include <hip/hip_runtime.h>
#include <cstdint>

typedef float f32x4 __attribute__((ext_vector_type(4)));
typedef __bf16 bf16x8 __attribute__((ext_vector_type(8)));
typedef __bf16 bf16x4 __attribute__((ext_vector_type(4)));

#define S_LEN 1248
#define S_PAD 1280
#define DIMD 2560
#define NHEAD 64
#define HDIM 40
#define T3 7680

__device__ __forceinline__ f32x4 mfma16(bf16x8 a, bf16x8 b, f32x4 c) {
  return __builtin_amdgcn_mfma_f32_16x16x32_bf16(a, b, c, 0, 0, 0);
}

// Chunked Bresenham block-splitter: chunks of 8 physical blocks are assigned to
// guest (returns true, idx = guest block id) or host (false, idx = host block id),
// spread evenly. Preserves (id & 7) == (blockIdx.x & 7) for both kinds, keeping
// the XCD swizzle property intact. Requires nHost%8==0 and nGuest%8==0.
__device__ __forceinline__ bool split8(int b, int nHostC, int nGuestC, int& idx) {
  int c = b >> 3, j = b & 7;
  int totc = nHostC + nGuestC;
  int tb = (int)(((long long)c * nGuestC) / totc);
  bool isG = ((long long)(c + 1) * nGuestC / totc) > tb;
  idx = (isG ? tb * 8 : (c - tb) * 8) + j;
  return isG;
}

// ================= device bodies =================

__device__ __forceinline__ void dev_trans(int vbid, const float* __restrict__ W,
                                          __bf16* __restrict__ Wt, int K, int N, char* smraw) {
  float (*t)[65] = (float(*)[65])smraw;
  int gxt = N >> 6;
  int n0 = (vbid % gxt) * 64, k0 = (vbid / gxt) * 64;
  int tid = threadIdx.x;
  #pragma unroll
  for (int i = 0; i < 4; ++i) {
    int r = i * 16 + (tid >> 4), c = (tid & 15) * 4;
    const float4 v = *(const float4*)&W[(size_t)(k0 + r) * N + n0 + c];
    t[r][c] = v.x; t[r][c + 1] = v.y; t[r][c + 2] = v.z; t[r][c + 3] = v.w;
  }
  __syncthreads();
  #pragma unroll
  for (int j = 0; j < 4; ++j) {
    int n = j * 16 + (tid >> 4), kk = (tid & 15) * 4;
    bf16x4 o;
    o[0] = (__bf16)t[kk][n];     o[1] = (__bf16)t[kk + 1][n];
    o[2] = (__bf16)t[kk + 2][n]; o[3] = (__bf16)t[kk + 3][n];
    *(bf16x4*)&Wt[(size_t)(n0 + n) * K + k0 + kk] = o;
  }
}

__device__ __forceinline__ void dev_lnmod(int row, const float* __restrict__ X,
                                          const float* __restrict__ ada,
                                          int csh_t, int csc_t, int csh_i, int csc_i,
                                          const int* __restrict__ tlp,
                                          __bf16* __restrict__ Y, char* smraw) {
  float* rs = (float*)smraw;
  float* rq = rs + 4;
  int tid = threadIdx.x;
  const float* x = X + (size_t)row * DIMD;
  float v[10], s = 0.f, s2 = 0.f;
  #pragma unroll
  for (int i = 0; i < 10; ++i) { v[i] = x[tid + i * 256]; s += v[i]; s2 += v[i] * v[i]; }
  #pragma unroll
  for (int m = 1; m < 64; m <<= 1) { s += __shfl_xor(s, m, 64); s2 += __shfl_xor(s2, m, 64); }
  if ((tid & 63) == 0) { rs[tid >> 6] = s; rq[tid >> 6] = s2; }
  __syncthreads();
  s = rs[0] + rs[1] + rs[2] + rs[3];
  s2 = rq[0] + rq[1] + rq[2] + rq[3];
  float mean = s * (1.f / DIMD);
  float rstd = rsqrtf(s2 * (1.f / DIMD) - mean * mean + 1e-6f);
  int txt = *tlp;
  int csh = row < txt ? csh_t : csh_i, csc = row < txt ? csc_t : csc_i;
  #pragma unroll
  for (int i = 0; i < 10; ++i) {
    int col = tid + i * 256;
    float y = (v[i] - mean) * rstd;
    y = y * (1.f + ada[csc * DIMD + col]) + ada[csh * DIMD + col];
    Y[(size_t)row * DIMD + col] = (__bf16)y;
  }
}

// GEMM (r4 structure): 128x128, triple-buffered prefetch-2, counted vmcnt, XCD swizzle.
// EPI 0: f32 +bias. EPI 2: gelu_tanh->bf16 (+bias). EPI 4: bf16 +bias.
// EPI 3: raw f32 partial (split-K; z=0 -> Cf, z>=1 -> Cp + (z-1)*S_PAD*N).
template <int EPI>
__device__ __forceinline__ void dev_gemm(int vbid, unsigned gx, unsigned gy, unsigned gz,
                                         const __bf16* __restrict__ A, int lda,
                                         const __bf16* __restrict__ Bt, int ldb,
                                         const float* __restrict__ bias, int N, int ksize,
                                         float* __restrict__ Cf, float* __restrict__ Cp,
                                         __bf16* __restrict__ Cb, char* smraw) {
  __bf16 (*smem)[2][4096] = (__bf16(*)[2][4096])smraw;
  int tid = threadIdx.x;

  unsigned nwg = gx * gy * gz;
  unsigned orig = (unsigned)vbid;
  unsigned qq = nwg >> 3, r8 = nwg & 7;
  unsigned xcd = orig & 7, loc = orig >> 3;
  unsigned swz = (xcd < r8 ? xcd * (qq + 1) : r8 * (qq + 1) + (xcd - r8) * qq) + loc;
  unsigned bx = swz % gx;
  unsigned rest = swz / gx;
  unsigned by = rest % gy;
  unsigned bz = rest / gy;

  int m0 = bx * 128, n0 = by * 128;
  int kbase = bz * ksize;
  int wave = tid >> 6, lane = tid & 63;
  int wm = (wave & 1) * 64, wn = (wave >> 1) * 64;
  int l15 = lane & 15, l4 = lane >> 4;
  f32x4 acc[4][4] = {};

  auto STG = [&](__bf16* As, __bf16* Bs, int kk) {
    #pragma unroll
    for (int i = 0; i < 2; ++i) {
      int c = tid + i * 256;
      int row = c >> 2, ko = (c & 3) * 8;
      __builtin_amdgcn_global_load_lds(
          (const __attribute__((address_space(1))) unsigned int*)(A + (size_t)(m0 + row) * lda + kk + ko),
          (__attribute__((address_space(3))) unsigned int*)(As + c * 8), 16, 0, 0);
      __builtin_amdgcn_global_load_lds(
          (const __attribute__((address_space(1))) unsigned int*)(Bt + (size_t)(n0 + row) * ldb + kk + ko),
          (__attribute__((address_space(3))) unsigned int*)(Bs + c * 8), 16, 0, 0);
    }
  };

  int nt = ksize >> 5;
  STG(smem[0][0], smem[0][1], kbase);
  STG(smem[1][0], smem[1][1], kbase + 32);
  asm volatile("s_waitcnt vmcnt(4)" ::: "memory");
  __builtin_amdgcn_s_barrier();

  int rb = 0, sb = 2;
  for (int t = 0; t < nt; ++t) {
    if (t + 2 < nt) STG(smem[sb][0], smem[sb][1], kbase + (t + 2) * 32);
    const __bf16* As = smem[rb][0];
    const __bf16* Bs = smem[rb][1];
    bf16x8 af[4], bfr[4];
    #pragma unroll
    for (int s = 0; s < 4; ++s) {
      af[s] = *(const bf16x8*)&As[(wm + s * 16 + l15) * 32 + l4 * 8];
      bfr[s] = *(const bf16x8*)&Bs[(wn + s * 16 + l15) * 32 + l4 * 8];
    }
    __builtin_amdgcn_s_setprio(1);
    #pragma unroll
    for (int i = 0; i < 4; ++i)
      #pragma unroll
      for (int j = 0; j < 4; ++j)
        acc[i][j] = mfma16(af[i], bfr[j], acc[i][j]);
    __builtin_amdgcn_s_setprio(0);
    __builtin_amdgcn_sched_barrier(0);
    if (t + 2 < nt)
      asm volatile("s_waitcnt vmcnt(4)" ::: "memory");
    else
      asm volatile("s_waitcnt vmcnt(0)" ::: "memory");
    __builtin_amdgcn_s_barrier();
    rb = rb == 2 ? 0 : rb + 1;
    sb = sb == 2 ? 0 : sb + 1;
  }

  float* Cfo = Cf;
  if constexpr (EPI == 3) Cfo = (bz == 0) ? Cf : (Cp + (size_t)(bz - 1) * S_PAD * N);
  #pragma unroll
  for (int i = 0; i < 4; ++i) {
    #pragma unroll
    for (int r = 0; r < 4; ++r) {
      int rr = m0 + wm + i * 16 + l4 * 4 + r;
      if (rr >= S_LEN) continue;
      #pragma unroll
      for (int j = 0; j < 4; ++j) {
        int col = n0 + wn + j * 16 + l15;
        if constexpr (EPI == 0) {
          Cfo[(size_t)rr * N + col] = acc[i][j][r] + bias[col];
        } else if constexpr (EPI == 3) {
          Cfo[(size_t)rr * N + col] = acc[i][j][r];
        } else if constexpr (EPI == 4) {
          Cb[(size_t)rr * N + col] = (__bf16)(acc[i][j][r] + bias[col]);
        } else {
          float val = acc[i][j][r] + bias[col];
          float u = val + 0.044715f * val * val * val;
          float gl = 0.5f * val * (1.f + tanhf(0.7978845608028654f * u));
          Cb[(size_t)rr * N + col] = (__bf16)gl;
        }
      }
    }
  }
}

// flash attention: LDS-staged K/V, double-buffered, fixed-max softmax (scores <= 6.33)
__device__ void dev_attn(int vbid, const __bf16* __restrict__ Qb,
                         const __bf16* __restrict__ Kb, const __bf16* __restrict__ Vt,
                         const float* __restrict__ mask, __bf16* __restrict__ ctx,
                         char* smraw) {
  __bf16 (*kvs)[2][4096] = (__bf16(*)[2][4096])smraw;
  __bf16 (*plds)[2][1024] = (__bf16(*)[2][1024])(smraw + 32768);
  unsigned orig = (unsigned)vbid;
  unsigned swz = (orig & 7) * 80 + (orig >> 3);
  int h = swz / 10, q0 = (swz % 10) * 128;
  int tid = threadIdx.x, wave = tid >> 6, lane = tid & 63;
  int l15 = lane & 15, l4 = lane >> 4;
  int qb = q0 + wave * 32;

  const __bf16* Kh = Kb + (size_t)h * S_PAD * 64;
  const __bf16* Vh = Vt + (size_t)h * 64 * S_PAD;

  auto STAGE = [&](int buf, int kv0) {
    #pragma unroll
    for (int i = 0; i < 2; ++i) {
      int c = tid + i * 256;
      int row = c >> 3, col = ((c & 7) ^ (row & 7)) * 8;
      __builtin_amdgcn_global_load_lds(
          (const __attribute__((address_space(1))) unsigned int*)(Kh + (size_t)(kv0 + row) * 64 + col),
          (__attribute__((address_space(3))) unsigned int*)&kvs[buf][0][c * 8], 16, 0, 0);
      __builtin_amdgcn_global_load_lds(
          (const __attribute__((address_space(1))) unsigned int*)(Vh + (size_t)row * S_PAD + kv0 + col),
          (__attribute__((address_space(3))) unsigned int*)&kvs[buf][1][c * 8], 16, 0, 0);
    }
  };

  bf16x8 qf[2][2];
  #pragma unroll
  for (int g = 0; g < 2; ++g) {
    const __bf16* Qp = Qb + ((size_t)h * S_PAD + qb + g * 16 + l15) * 64 + l4 * 8;
    qf[g][0] = *(const bf16x8*)Qp;
    qf[g][1] = *(const bf16x8*)(Qp + 32);
  }
  const float* mrow[2][4];
  #pragma unroll
  for (int g = 0; g < 2; ++g)
    #pragma unroll
    for (int r = 0; r < 4; ++r) {
      int qr = qb + g * 16 + l4 * 4 + r;
      mrow[g][r] = mask + (size_t)(qr < S_LEN ? qr : S_LEN - 1) * S_LEN;
    }
  f32x4 o[2][3] = {};

  STAGE(0, 0);
  for (int t = 0; t < 20; ++t) {
    int kv0 = t * 64;
    if (t < 19) {
      STAGE((t + 1) & 1, kv0 + 64);
      asm volatile("s_waitcnt vmcnt(4)" ::: "memory");
    } else {
      asm volatile("s_waitcnt vmcnt(0)" ::: "memory");
    }
    __builtin_amdgcn_s_barrier();
    const __bf16* Ks = kvs[t & 1][0];
    const __bf16* Vs = kvs[t & 1][1];

    float mreg[2][4][4];
    #pragma unroll
    for (int g = 0; g < 2; ++g)
      #pragma unroll
      for (int ns = 0; ns < 4; ++ns) {
        int kvc = kv0 + ns * 16 + l15;
        int mc = kvc < S_LEN ? kvc : S_LEN - 1;
        #pragma unroll
        for (int r = 0; r < 4; ++r) mreg[g][ns][r] = mrow[g][r][mc];
      }

    bf16x8 kf[4][2];
    #pragma unroll
    for (int ns = 0; ns < 4; ++ns) {
      int kvr = ns * 16 + l15, sw = kvr & 7;
      kf[ns][0] = *(const bf16x8*)((const char*)Ks + kvr * 128 + ((l4 ^ sw) << 4));
      kf[ns][1] = *(const bf16x8*)((const char*)Ks + kvr * 128 + (((4 + l4) ^ sw) << 4));
    }
    bf16x8 vf[3][2];
    #pragma unroll
    for (int d3 = 0; d3 < 3; ++d3) {
      int dr = d3 * 16 + l15, sw = dr & 7;
      vf[d3][0] = *(const bf16x8*)((const char*)Vs + dr * 128 + ((l4 ^ sw) << 4));
      vf[d3][1] = *(const bf16x8*)((const char*)Vs + dr * 128 + (((4 + l4) ^ sw) << 4));
    }

    #pragma unroll
    for (int g = 0; g < 2; ++g) {
      f32x4 sf[4];
      #pragma unroll
      for (int ns = 0; ns < 4; ++ns) {
        f32x4 a = {};
        a = mfma16(qf[g][0], kf[ns][0], a);
        a = mfma16(qf[g][1], kf[ns][1], a);
        sf[ns] = a;
      }
      #pragma unroll
      for (int ns = 0; ns < 4; ++ns) {
        int kvc = kv0 + ns * 16 + l15;
        #pragma unroll
        for (int r = 0; r < 4; ++r) {
          float val = sf[ns][r] - 8.f + mreg[g][ns][r];
          if (kvc >= S_LEN) val = -100.f;
          float e = __expf(val);
          int prow = l4 * 4 + r;
          int boff = (prow * 128 + (ns * 16 + l15) * 2) ^ ((prow & 7) << 4);
          plds[wave][g][boff >> 1] = (__bf16)e;
        }
      }
      int swp = (l15 & 7) << 4;
      int ba = l15 * 128 + l4 * 16;
      bf16x8 pa0 = *(const bf16x8*)((const char*)plds[wave][g] + (ba ^ swp));
      bf16x8 pa1 = *(const bf16x8*)((const char*)plds[wave][g] + ((ba + 64) ^ swp));
      #pragma unroll
      for (int d3 = 0; d3 < 3; ++d3) {
        o[g][d3] = mfma16(pa0, vf[d3][0], o[g][d3]);
        o[g][d3] = mfma16(pa1, vf[d3][1], o[g][d3]);
      }
    }
    __builtin_amdgcn_s_barrier();
  }

  #pragma unroll
  for (int g = 0; g < 2; ++g) {
    #pragma unroll
    for (int r = 0; r < 4; ++r) {
      float sum = __shfl(o[g][2][r], (lane & 0x30) + 8, 64);
      float rinv = 1.f / sum;
      int qr = qb + g * 16 + l4 * 4 + r;
      if (qr < S_LEN) {
        #pragma unroll
        for (int d3 = 0; d3 < 3; ++d3) {
          int d = d3 * 16 + l15;
          if (d < HDIM)
            ctx[(size_t)qr * DIMD + h * HDIM + d] = (__bf16)(o[g][d3][r] * rinv);
        }
      }
    }
  }
}

// ================= kernels =================

__global__ void k_adaln(const float* __restrict__ emb, const float* __restrict__ W,
                        const float* __restrict__ b, float* __restrict__ ada) {
  __shared__ __attribute__((aligned(16))) float se[512];
  int tid = threadIdx.x;
  for (int i = tid; i < 512; i += 64) {
    float e = emb[i];
    se[i] = e / (1.f + __expf(-e));
  }
  __syncthreads();
  int col = blockIdx.x * 64 + tid;
  float acc = 0.f;
  #pragma unroll 8
  for (int k = 0; k < 512; ++k) acc += se[k] * W[(size_t)k * 30720 + col];
  ada[col] = acc + b[col];
}

// lnmod(1248) + qkv_w transpose(4800) fused, interleaved
__global__ __launch_bounds__(256) void k_lnmod_qtrans(const float* __restrict__ X,
                                                      const float* __restrict__ ada,
                                                      const int* __restrict__ tlp,
                                                      __bf16* __restrict__ Y,
                                                      const float* __restrict__ W,
                                                      __bf16* __restrict__ Wt) {
  __shared__ __attribute__((aligned(16))) char sm[16640];
  int idx;
  if (split8(blockIdx.x, 1248 / 8, 4800 / 8, idx)) dev_trans(idx, W, Wt, 2560, 7680, sm);
  else dev_lnmod(idx, X, ada, 6, 7, 0, 1, tlp, Y, sm);
}

// GEMM + weight-transpose fused, interleaved (host counts must be %8==0)
template <int EPI>
__global__ __launch_bounds__(256) void k_gemm_trans(
    const __bf16* __restrict__ A, int lda, const __bf16* __restrict__ Bt, int ldb,
    const float* __restrict__ bias, int N, int ksize,
    float* __restrict__ Cf, float* __restrict__ Cp, __bf16* __restrict__ Cb,
    unsigned gx, unsigned gy, unsigned gz, int nT,
    const float* __restrict__ W, __bf16* __restrict__ Wt, int tK, int tN) {
  __shared__ __attribute__((aligned(16))) char sm[49152];
  int nG = (int)(gx * gy * gz);
  int idx;
  if (split8(blockIdx.x, nG >> 3, nT >> 3, idx)) dev_trans(idx, W, Wt, tK, tN, sm);
  else dev_gemm<EPI>(idx, gx, gy, gz, A, lda, Bt, ldb, bias, N, ksize, Cf, Cp, Cb, sm);
}

// plain GEMM
template <int EPI>
__global__ __launch_bounds__(256) void k_gemm(
    const __bf16* __restrict__ A, int lda, const __bf16* __restrict__ Bt, int ldb,
    const float* __restrict__ bias, int N, int ksize,
    float* __restrict__ Cf, float* __restrict__ Cp, __bf16* __restrict__ Cb) {
  __shared__ __attribute__((aligned(16))) char sm[49152];
  int vbid = (blockIdx.z * gridDim.y + blockIdx.y) * gridDim.x + blockIdx.x;
  dev_gemm<EPI>(vbid, gridDim.x, gridDim.y, gridDim.z, A, lda, Bt, ldb, bias, N, ksize,
                Cf, Cp, Cb, sm);
}

// attention(640) + ff1_w transpose(6400) fused, interleaved
__global__ __launch_bounds__(256) void k_attn_trans(const __bf16* __restrict__ Qb,
                                                    const __bf16* __restrict__ Kb,
                                                    const __bf16* __restrict__ Vt,
                                                    const float* __restrict__ mask,
                                                    __bf16* __restrict__ ctx,
                                                    const float* __restrict__ W,
                                                    __bf16* __restrict__ Wt, int tK, int tN) {
  __shared__ __attribute__((aligned(16))) char sm[49152];
  int idx;
  if (split8(blockIdx.x, 640 / 8, 6400 / 8, idx)) dev_trans(idx, W, Wt, tK, tN, sm);
  else dev_attn(idx, Qb, Kb, Vt, mask, ctx, sm);
}

// qkv-prep fused: per-head q/k LN (624 blocks, 2 rows each) + V transpose (1280 blocks)
__global__ __launch_bounds__(256) void k_qkvprep(const __bf16* __restrict__ qkv,
                                                 __bf16* __restrict__ Qb,
                                                 __bf16* __restrict__ Kb,
                                                 __bf16* __restrict__ Vt) {
  __shared__ __attribute__((aligned(16))) char sm[40960];
  int b = blockIdx.x, tid = threadIdx.x;
  if (b < 624) {
    float (*buf)[5120] = (float(*)[5120])sm;
    int sub = tid >> 7, t2 = tid & 127;
    int srow = b * 2 + sub;
    const __bf16* rowp = qkv + (size_t)srow * T3;
    for (int i = t2; i < 640; i += 128) {
      bf16x8 v = *(const bf16x8*)&rowp[i * 8];
      #pragma unroll
      for (int j = 0; j < 8; ++j) buf[sub][i * 8 + j] = (float)v[j];
    }
    __syncthreads();
    int h = t2 & 63;
    bool isK = t2 >= 64;
    const float* x = buf[sub] + (isK ? DIMD : 0) + h * HDIM;
    float xv[40], s = 0.f;
    #pragma unroll
    for (int d = 0; d < 40; ++d) { xv[d] = x[d]; s += xv[d]; }
    float mean = s * (1.f / 40.f);
    float s2 = 0.f;
    #pragma unroll
    for (int d = 0; d < 40; ++d) { float t = xv[d] - mean; s2 += t * t; }
    float rstd = rsqrtf(s2 * (1.f / 40.f) + 1e-6f);
    float scale = isK ? rstd : rstd * 0.15811388300841897f;
    __bf16* dst = (isK ? Kb : Qb) + ((size_t)h * S_PAD + srow) * 64;
    #pragma unroll
    for (int i = 0; i < 5; ++i) {
      bf16x8 w;
      #pragma unroll
      for (int j = 0; j < 8; ++j) w[j] = (__bf16)((xv[i * 8 + j] - mean) * scale);
      *(bf16x8*)&dst[i * 8] = w;
    }
    bf16x8 z = {};
    *(bf16x8*)&dst[40] = z;
    *(bf16x8*)&dst[48] = z;
    *(bf16x8*)&dst[56] = z;
  } else {
    float (*t)[41] = (float(*)[41])sm;
    int vbid = b - 624;
    int h = vbid / 20, s0 = (vbid % 20) * 64;
    for (int i = tid; i < 64 * 40; i += 256) {
      int sr = i / 40, d = i - sr * 40;
      int srow = s0 + sr;
      t[sr][d] = (srow < S_LEN) ? (float)qkv[(size_t)srow * T3 + 2 * DIMD + h * HDIM + d] : 0.f;
    }
    __syncthreads();
    int d = tid >> 2, sc = (tid & 3) * 16;
    bf16x8 w0 = {}, w1 = {};
    if (d < 40) {
      #pragma unroll
      for (int q = 0; q < 8; ++q) {
        w0[q] = (__bf16)t[sc + q][d];
        w1[q] = (__bf16)t[sc + 8 + q][d];
      }
    } else if (d == 40) {
      #pragma unroll
      for (int q = 0; q < 8; ++q) { w0[q] = (__bf16)1.0f; w1[q] = (__bf16)1.0f; }
    }
    __bf16* dst = Vt + ((size_t)h * 64 + d) * S_PAD + s0 + sc;
    *(bf16x8*)&dst[0] = w0;
    *(bf16x8*)&dst[8] = w1;
  }
}

// fused: split-K2 reduce + bias + gated residual -> h (f32), then LN + modulate -> bf16
__global__ __launch_bounds__(256) void k_redln(const float* __restrict__ p0,
                                               const float* __restrict__ p1,
                                               const float* __restrict__ bias,
                                               const float* __restrict__ resid,
                                               const float* __restrict__ ada,
                                               int g_t, int g_i,
                                               int csh_t, int csc_t, int csh_i, int csc_i,
                                               const int* __restrict__ tlp,
                                               float* __restrict__ hout,
                                               __bf16* __restrict__ Y) {
  __shared__ float rs[4], rq[4];
  int row = blockIdx.x, tid = threadIdx.x;
  int txt = *tlp;
  bool isTxt = row < txt;
  size_t off = (size_t)row * DIMD;
  const float* gp = ada + (size_t)(isTxt ? g_t : g_i) * DIMD;
  float v[10], s = 0.f, s2 = 0.f;
  #pragma unroll
  for (int i = 0; i < 10; ++i) {
    int col = tid + i * 256;
    float val = p0[off + col] + p1[off + col] + bias[col];
    float hh = resid[off + col] + gp[col] * val;
    hout[off + col] = hh;
    v[i] = hh; s += hh; s2 += hh * hh;
  }
  #pragma unroll
  for (int m = 1; m < 64; m <<= 1) { s += __shfl_xor(s, m, 64); s2 += __shfl_xor(s2, m, 64); }
  if ((tid & 63) == 0) { rs[tid >> 6] = s; rq[tid >> 6] = s2; }
  __syncthreads();
  s = rs[0] + rs[1] + rs[2] + rs[3];
  s2 = rq[0] + rq[1] + rq[2] + rq[3];
  float mean = s * (1.f / DIMD);
  float rstd = rsqrtf(s2 * (1.f / DIMD) - mean * mean + 1e-6f);
  int csh = isTxt ? csh_t : csh_i, csc = isTxt ? csc_t : csc_i;
  #pragma unroll
  for (int i = 0; i < 10; ++i) {
    int col = tid + i * 256;
    float y = (v[i] - mean) * rstd;
    y = y * (1.f + ada[csc * DIMD + col]) + ada[csh * DIMD + col];
    Y[off + col] = (__bf16)y;
  }
}

// split-K reduce (2 slices) + bias + gated residual (final output)
__global__ __launch_bounds__(256) void k_red2(const float* __restrict__ p0,
                                              const float* __restrict__ p1,
                                              const float* __restrict__ bias,
                                              const float* __restrict__ resid,
                                              const float* __restrict__ ada,
                                              int g_t, int g_i, const int* __restrict__ tlp,
                                              float* __restrict__ out) {
  int idx = blockIdx.x * 256 + threadIdx.x;
  int perRow = DIMD >> 2;
  int row = idx / perRow;
  int c4 = (idx - row * perRow) << 2;
  if (row >= S_LEN) return;
  int txt = *tlp;
  size_t off = (size_t)row * DIMD + c4;
  const float4 a = *(const float4*)&p0[off];
  const float4 p = *(const float4*)&p1[off];
  const float4 bb = *(const float4*)&bias[c4];
  const float4 rr = *(const float4*)&resid[off];
  const float4 gg = *(const float4*)&ada[(size_t)(row < txt ? g_t : g_i) * DIMD + c4];
  float4 o;
  o.x = rr.x + gg.x * (a.x + p.x + bb.x);
  o.y = rr.y + gg.y * (a.y + p.y + bb.y);
  o.z = rr.z + gg.z * (a.z + p.z + bb.z);
  o.w = rr.w + gg.w * (a.w + p.w + bb.w);
  *(float4*)&out[off] = o;
}

extern "C" void kernel_launch(void* const* d_in, const int* in_sizes, int n_in,
                              void* d_out, int out_size, void* d_ws, size_t ws_size,
                              hipStream_t stream) {
  const float* hidden  = (const float*)d_in[0];
  const float* emb     = (const float*)d_in[1];
  const float* mask    = (const float*)d_in[2];
  const float* adaln_w = (const float*)d_in[3];
  const float* adaln_b = (const float*)d_in[4];
  const float* qkv_w   = (const float*)d_in[5];
  const float* qkv_b   = (const float*)d_in[6];
  const float* out_w   = (const float*)d_in[7];
  const float* out_b   = (const float*)d_in[8];
  const float* ff1_w   = (const float*)d_in[9];
  const float* ff1_b   = (const float*)d_in[10];
  const float* ff2_w   = (const float*)d_in[11];
  const float* ff2_b   = (const float*)d_in[12];
  const int*   tl      = (const int*)d_in[13];
  (void)in_sizes; (void)n_in; (void)out_size; (void)ws_size;

  char* w = (char*)d_ws;
  size_t off = 0;
  auto alloc = [&](size_t b) { char* p = w + off; off += (b + 255) & ~(size_t)255; return p; };
  float*  ada  = (float*)alloc(30720 * 4);
  __bf16* wTf1 = (__bf16*)alloc((size_t)10240 * 2560 * 2);       // ff1_w (52.4MB)
  __bf16* wTq2 = (__bf16*)alloc((size_t)10240 * 2560 * 2);       // qkv_w then ff2_w (52.4MB)
  __bf16* ai   = (__bf16*)alloc((size_t)S_PAD * DIMD * 2);       // lnmod out / mi
  __bf16* actB = (__bf16*)alloc((size_t)S_PAD * 10240 * 2);      // qkvB then ff1o (26.2MB)
  __bf16* Qb   = (__bf16*)alloc((size_t)NHEAD * S_PAD * 64 * 2);
  __bf16* Kb   = (__bf16*)alloc((size_t)NHEAD * S_PAD * 64 * 2);
  __bf16* Vt   = (__bf16*)alloc((size_t)NHEAD * 64 * S_PAD * 2);
  __bf16* ctxb = (__bf16*)alloc((size_t)S_PAD * DIMD * 2);
  float*  hbuf = (float*)alloc((size_t)S_PAD * DIMD * 4);        // out_w-trans region, then h
  __bf16* mi    = ai;
  __bf16* qkvB  = actB;
  __bf16* ff1o  = actB;
  __bf16* wTo   = (__bf16*)hbuf;  // out_w bf16 13.1MB, dead before k_redln writes hbuf
  float*  partO = (float*)Qb;     // out-proj partials 2x13.1MB over Qb+Kb+Vt (dead after attn)
  float*  partF = (float*)Qb;     // ff2 partials (same region, dead after redln)

  k_adaln<<<dim3(480), dim3(64), 0, stream>>>(emb, adaln_w, adaln_b, ada);
  // lnmod (1248) || qkv_w transpose (4800), interleaved
  k_lnmod_qtrans<<<dim3(1248 + 4800), dim3(256), 0, stream>>>(hidden, ada, tl, ai, qkv_w, wTq2);
  // qkv GEMM (600, bf16 out EPI4) || out_w transpose (1600 -> wTo), interleaved
  k_gemm_trans<4><<<dim3(600 + 1600), dim3(256), 0, stream>>>(
      ai, 2560, wTq2, 2560, qkv_b, 7680, 2560, nullptr, nullptr, qkvB,
      10, 60, 1, 1600, out_w, wTo, 2560, 2560);
  // q/k LN (624) || V transpose (1280)
  k_qkvprep<<<dim3(624 + 1280), dim3(256), 0, stream>>>(qkvB, Qb, Kb, Vt);
  // attention (640) || ff1_w transpose (6400), interleaved
  k_attn_trans<<<dim3(640 + 6400), dim3(256), 0, stream>>>(Qb, Kb, Vt, mask, ctxb,
                                                           ff1_w, wTf1, 2560, 10240);
  // out-proj: plain split-K=2 (400)
  k_gemm<3><<<dim3(10, 20, 2), dim3(256), 0, stream>>>(ctxb, 2560, wTo, 2560, nullptr, 2560, 1280,
                                                       partO, partO + (size_t)S_PAD * 2560, nullptr);
  // fused: reduce+residual -> hbuf, LN+modulate -> mi
  k_redln<<<dim3(1248), dim3(256), 0, stream>>>(partO, partO + (size_t)S_PAD * 2560, out_b,
                                                hidden, ada, 8, 2, 9, 10, 3, 4, tl, hbuf, mi);
  // ff1 GEMM (800, gelu EPI2) || ff2_w transpose (6400 -> wTq2), interleaved
  k_gemm_trans<2><<<dim3(800 + 6400), dim3(256), 0, stream>>>(
      mi, 2560, wTf1, 2560, ff1_b, 10240, 2560, nullptr, nullptr, ff1o,
      10, 80, 1, 6400, ff2_w, wTq2, 10240, 2560);
  // ff2: split-K=2 (400 blocks, 80 steps)
  k_gemm<3><<<dim3(10, 20, 2), dim3(256), 0, stream>>>(ff1o, 10240, wTq2, 10240, nullptr, 2560, 5120,
                                                       partF, partF + (size_t)S_PAD * 2560, nullptr);
  k_red2<<<dim3(3120), dim3(256), 0, stream>>>(partF, partF + (size_t)S_PAD * 2560, ff2_b,
                                               hbuf, ada, 11, 5, tl, (float*)d_out);
}

// Round 14
// 509.952 us; speedup vs baseline: 1.1423x; 1.1423x over previous
//
#include <hip/hip_runtime.h>
#include <cstdint>

typedef float f32x4 __attribute__((ext_vector_type(4)));
typedef __bf16 bf16x8 __attribute__((ext_vector_type(8)));
typedef __bf16 bf16x4 __attribute__((ext_vector_type(4)));

#define S_LEN 1248
#define S_PAD 1280
#define DIMD 2560
#define NHEAD 64
#define HDIM 40
#define T3 7680

__device__ __forceinline__ f32x4 mfma16(bf16x8 a, bf16x8 b, f32x4 c) {
  return __builtin_amdgcn_mfma_f32_16x16x32_bf16(a, b, c, 0, 0, 0);
}

// ================= device bodies =================

__device__ __forceinline__ void dev_trans(int vbid, const float* __restrict__ W,
                                          __bf16* __restrict__ Wt, int K, int N, char* smraw) {
  float (*t)[65] = (float(*)[65])smraw;
  int gxt = N >> 6;
  int n0 = (vbid % gxt) * 64, k0 = (vbid / gxt) * 64;
  int tid = threadIdx.x;
  #pragma unroll
  for (int i = 0; i < 4; ++i) {
    int r = i * 16 + (tid >> 4), c = (tid & 15) * 4;
    const float4 v = *(const float4*)&W[(size_t)(k0 + r) * N + n0 + c];
    t[r][c] = v.x; t[r][c + 1] = v.y; t[r][c + 2] = v.z; t[r][c + 3] = v.w;
  }
  __syncthreads();
  #pragma unroll
  for (int j = 0; j < 4; ++j) {
    int n = j * 16 + (tid >> 4), kk = (tid & 15) * 4;
    bf16x4 o;
    o[0] = (__bf16)t[kk][n];     o[1] = (__bf16)t[kk + 1][n];
    o[2] = (__bf16)t[kk + 2][n]; o[3] = (__bf16)t[kk + 3][n];
    *(bf16x4*)&Wt[(size_t)(n0 + n) * K + k0 + kk] = o;
  }
}

__device__ __forceinline__ void dev_lnmod(int row, const float* __restrict__ X,
                                          const float* __restrict__ ada,
                                          int csh_t, int csc_t, int csh_i, int csc_i,
                                          const int* __restrict__ tlp,
                                          __bf16* __restrict__ Y, char* smraw) {
  float* rs = (float*)smraw;
  float* rq = rs + 4;
  int tid = threadIdx.x;
  const float* x = X + (size_t)row * DIMD;
  float v[10], s = 0.f, s2 = 0.f;
  #pragma unroll
  for (int i = 0; i < 10; ++i) { v[i] = x[tid + i * 256]; s += v[i]; s2 += v[i] * v[i]; }
  #pragma unroll
  for (int m = 1; m < 64; m <<= 1) { s += __shfl_xor(s, m, 64); s2 += __shfl_xor(s2, m, 64); }
  if ((tid & 63) == 0) { rs[tid >> 6] = s; rq[tid >> 6] = s2; }
  __syncthreads();
  s = rs[0] + rs[1] + rs[2] + rs[3];
  s2 = rq[0] + rq[1] + rq[2] + rq[3];
  float mean = s * (1.f / DIMD);
  float rstd = rsqrtf(s2 * (1.f / DIMD) - mean * mean + 1e-6f);
  int txt = *tlp;
  int csh = row < txt ? csh_t : csh_i, csc = row < txt ? csc_t : csc_i;
  #pragma unroll
  for (int i = 0; i < 10; ++i) {
    int col = tid + i * 256;
    float y = (v[i] - mean) * rstd;
    y = y * (1.f + ada[csc * DIMD + col]) + ada[csh * DIMD + col];
    Y[(size_t)row * DIMD + col] = (__bf16)y;
  }
}

// GEMM (r4 structure): 128x128, triple-buffered prefetch-2, counted vmcnt, XCD swizzle.
// EPI 0: f32 +bias. EPI 2: gelu_tanh->bf16 (+bias). EPI 4: bf16 +bias.
// EPI 3: raw f32 partial (split-K; z=0 -> Cf, z>=1 -> Cp + (z-1)*S_PAD*N).
template <int EPI>
__device__ __forceinline__ void dev_gemm(int vbid, unsigned gx, unsigned gy, unsigned gz,
                                         const __bf16* __restrict__ A, int lda,
                                         const __bf16* __restrict__ Bt, int ldb,
                                         const float* __restrict__ bias, int N, int ksize,
                                         float* __restrict__ Cf, float* __restrict__ Cp,
                                         __bf16* __restrict__ Cb, char* smraw) {
  __bf16 (*smem)[2][4096] = (__bf16(*)[2][4096])smraw;
  int tid = threadIdx.x;

  unsigned nwg = gx * gy * gz;
  unsigned orig = (unsigned)vbid;
  unsigned qq = nwg >> 3, r8 = nwg & 7;
  unsigned xcd = orig & 7, loc = orig >> 3;
  unsigned swz = (xcd < r8 ? xcd * (qq + 1) : r8 * (qq + 1) + (xcd - r8) * qq) + loc;
  unsigned bx = swz % gx;
  unsigned rest = swz / gx;
  unsigned by = rest % gy;
  unsigned bz = rest / gy;

  int m0 = bx * 128, n0 = by * 128;
  int kbase = bz * ksize;
  int wave = tid >> 6, lane = tid & 63;
  int wm = (wave & 1) * 64, wn = (wave >> 1) * 64;
  int l15 = lane & 15, l4 = lane >> 4;
  f32x4 acc[4][4] = {};

  auto STG = [&](__bf16* As, __bf16* Bs, int kk) {
    #pragma unroll
    for (int i = 0; i < 2; ++i) {
      int c = tid + i * 256;
      int row = c >> 2, ko = (c & 3) * 8;
      __builtin_amdgcn_global_load_lds(
          (const __attribute__((address_space(1))) unsigned int*)(A + (size_t)(m0 + row) * lda + kk + ko),
          (__attribute__((address_space(3))) unsigned int*)(As + c * 8), 16, 0, 0);
      __builtin_amdgcn_global_load_lds(
          (const __attribute__((address_space(1))) unsigned int*)(Bt + (size_t)(n0 + row) * ldb + kk + ko),
          (__attribute__((address_space(3))) unsigned int*)(Bs + c * 8), 16, 0, 0);
    }
  };

  int nt = ksize >> 5;
  STG(smem[0][0], smem[0][1], kbase);
  STG(smem[1][0], smem[1][1], kbase + 32);
  asm volatile("s_waitcnt vmcnt(4)" ::: "memory");
  __builtin_amdgcn_s_barrier();

  int rb = 0, sb = 2;
  for (int t = 0; t < nt; ++t) {
    if (t + 2 < nt) STG(smem[sb][0], smem[sb][1], kbase + (t + 2) * 32);
    const __bf16* As = smem[rb][0];
    const __bf16* Bs = smem[rb][1];
    bf16x8 af[4], bfr[4];
    #pragma unroll
    for (int s = 0; s < 4; ++s) {
      af[s] = *(const bf16x8*)&As[(wm + s * 16 + l15) * 32 + l4 * 8];
      bfr[s] = *(const bf16x8*)&Bs[(wn + s * 16 + l15) * 32 + l4 * 8];
    }
    __builtin_amdgcn_s_setprio(1);
    #pragma unroll
    for (int i = 0; i < 4; ++i)
      #pragma unroll
      for (int j = 0; j < 4; ++j)
        acc[i][j] = mfma16(af[i], bfr[j], acc[i][j]);
    __builtin_amdgcn_s_setprio(0);
    __builtin_amdgcn_sched_barrier(0);
    if (t + 2 < nt)
      asm volatile("s_waitcnt vmcnt(4)" ::: "memory");
    else
      asm volatile("s_waitcnt vmcnt(0)" ::: "memory");
    __builtin_amdgcn_s_barrier();
    rb = rb == 2 ? 0 : rb + 1;
    sb = sb == 2 ? 0 : sb + 1;
  }

  float* Cfo = Cf;
  if constexpr (EPI == 3) Cfo = (bz == 0) ? Cf : (Cp + (size_t)(bz - 1) * S_PAD * N);
  #pragma unroll
  for (int i = 0; i < 4; ++i) {
    #pragma unroll
    for (int r = 0; r < 4; ++r) {
      int rr = m0 + wm + i * 16 + l4 * 4 + r;
      if (rr >= S_LEN) continue;
      #pragma unroll
      for (int j = 0; j < 4; ++j) {
        int col = n0 + wn + j * 16 + l15;
        if constexpr (EPI == 0) {
          Cfo[(size_t)rr * N + col] = acc[i][j][r] + bias[col];
        } else if constexpr (EPI == 3) {
          Cfo[(size_t)rr * N + col] = acc[i][j][r];
        } else if constexpr (EPI == 4) {
          Cb[(size_t)rr * N + col] = (__bf16)(acc[i][j][r] + bias[col]);
        } else {
          float val = acc[i][j][r] + bias[col];
          float u = val + 0.044715f * val * val * val;
          float gl = 0.5f * val * (1.f + tanhf(0.7978845608028654f * u));
          Cb[(size_t)rr * N + col] = (__bf16)gl;
        }
      }
    }
  }
}

// flash attention: LDS-staged K/V, double-buffered, fixed-max softmax (scores <= 6.33)
__device__ void dev_attn(int vbid, const __bf16* __restrict__ Qb,
                         const __bf16* __restrict__ Kb, const __bf16* __restrict__ Vt,
                         const float* __restrict__ mask, __bf16* __restrict__ ctx,
                         char* smraw) {
  __bf16 (*kvs)[2][4096] = (__bf16(*)[2][4096])smraw;
  __bf16 (*plds)[2][1024] = (__bf16(*)[2][1024])(smraw + 32768);
  unsigned orig = (unsigned)vbid;
  unsigned swz = (orig & 7) * 80 + (orig >> 3);
  int h = swz / 10, q0 = (swz % 10) * 128;
  int tid = threadIdx.x, wave = tid >> 6, lane = tid & 63;
  int l15 = lane & 15, l4 = lane >> 4;
  int qb = q0 + wave * 32;

  const __bf16* Kh = Kb + (size_t)h * S_PAD * 64;
  const __bf16* Vh = Vt + (size_t)h * 64 * S_PAD;

  auto STAGE = [&](int buf, int kv0) {
    #pragma unroll
    for (int i = 0; i < 2; ++i) {
      int c = tid + i * 256;
      int row = c >> 3, col = ((c & 7) ^ (row & 7)) * 8;
      __builtin_amdgcn_global_load_lds(
          (const __attribute__((address_space(1))) unsigned int*)(Kh + (size_t)(kv0 + row) * 64 + col),
          (__attribute__((address_space(3))) unsigned int*)&kvs[buf][0][c * 8], 16, 0, 0);
      __builtin_amdgcn_global_load_lds(
          (const __attribute__((address_space(1))) unsigned int*)(Vh + (size_t)row * S_PAD + kv0 + col),
          (__attribute__((address_space(3))) unsigned int*)&kvs[buf][1][c * 8], 16, 0, 0);
    }
  };

  bf16x8 qf[2][2];
  #pragma unroll
  for (int g = 0; g < 2; ++g) {
    const __bf16* Qp = Qb + ((size_t)h * S_PAD + qb + g * 16 + l15) * 64 + l4 * 8;
    qf[g][0] = *(const bf16x8*)Qp;
    qf[g][1] = *(const bf16x8*)(Qp + 32);
  }
  const float* mrow[2][4];
  #pragma unroll
  for (int g = 0; g < 2; ++g)
    #pragma unroll
    for (int r = 0; r < 4; ++r) {
      int qr = qb + g * 16 + l4 * 4 + r;
      mrow[g][r] = mask + (size_t)(qr < S_LEN ? qr : S_LEN - 1) * S_LEN;
    }
  f32x4 o[2][3] = {};

  STAGE(0, 0);
  for (int t = 0; t < 20; ++t) {
    int kv0 = t * 64;
    if (t < 19) {
      STAGE((t + 1) & 1, kv0 + 64);
      asm volatile("s_waitcnt vmcnt(4)" ::: "memory");
    } else {
      asm volatile("s_waitcnt vmcnt(0)" ::: "memory");
    }
    __builtin_amdgcn_s_barrier();
    const __bf16* Ks = kvs[t & 1][0];
    const __bf16* Vs = kvs[t & 1][1];

    float mreg[2][4][4];
    #pragma unroll
    for (int g = 0; g < 2; ++g)
      #pragma unroll
      for (int ns = 0; ns < 4; ++ns) {
        int kvc = kv0 + ns * 16 + l15;
        int mc = kvc < S_LEN ? kvc : S_LEN - 1;
        #pragma unroll
        for (int r = 0; r < 4; ++r) mreg[g][ns][r] = mrow[g][r][mc];
      }

    bf16x8 kf[4][2];
    #pragma unroll
    for (int ns = 0; ns < 4; ++ns) {
      int kvr = ns * 16 + l15, sw = kvr & 7;
      kf[ns][0] = *(const bf16x8*)((const char*)Ks + kvr * 128 + ((l4 ^ sw) << 4));
      kf[ns][1] = *(const bf16x8*)((const char*)Ks + kvr * 128 + (((4 + l4) ^ sw) << 4));
    }
    bf16x8 vf[3][2];
    #pragma unroll
    for (int d3 = 0; d3 < 3; ++d3) {
      int dr = d3 * 16 + l15, sw = dr & 7;
      vf[d3][0] = *(const bf16x8*)((const char*)Vs + dr * 128 + ((l4 ^ sw) << 4));
      vf[d3][1] = *(const bf16x8*)((const char*)Vs + dr * 128 + (((4 + l4) ^ sw) << 4));
    }

    #pragma unroll
    for (int g = 0; g < 2; ++g) {
      f32x4 sf[4];
      #pragma unroll
      for (int ns = 0; ns < 4; ++ns) {
        f32x4 a = {};
        a = mfma16(qf[g][0], kf[ns][0], a);
        a = mfma16(qf[g][1], kf[ns][1], a);
        sf[ns] = a;
      }
      #pragma unroll
      for (int ns = 0; ns < 4; ++ns) {
        int kvc = kv0 + ns * 16 + l15;
        #pragma unroll
        for (int r = 0; r < 4; ++r) {
          float val = sf[ns][r] - 8.f + mreg[g][ns][r];
          if (kvc >= S_LEN) val = -100.f;
          float e = __expf(val);
          int prow = l4 * 4 + r;
          int boff = (prow * 128 + (ns * 16 + l15) * 2) ^ ((prow & 7) << 4);
          plds[wave][g][boff >> 1] = (__bf16)e;
        }
      }
      int swp = (l15 & 7) << 4;
      int ba = l15 * 128 + l4 * 16;
      bf16x8 pa0 = *(const bf16x8*)((const char*)plds[wave][g] + (ba ^ swp));
      bf16x8 pa1 = *(const bf16x8*)((const char*)plds[wave][g] + ((ba + 64) ^ swp));
      #pragma unroll
      for (int d3 = 0; d3 < 3; ++d3) {
        o[g][d3] = mfma16(pa0, vf[d3][0], o[g][d3]);
        o[g][d3] = mfma16(pa1, vf[d3][1], o[g][d3]);
      }
    }
    __builtin_amdgcn_s_barrier();
  }

  #pragma unroll
  for (int g = 0; g < 2; ++g) {
    #pragma unroll
    for (int r = 0; r < 4; ++r) {
      float sum = __shfl(o[g][2][r], (lane & 0x30) + 8, 64);
      float rinv = 1.f / sum;
      int qr = qb + g * 16 + l4 * 4 + r;
      if (qr < S_LEN) {
        #pragma unroll
        for (int d3 = 0; d3 < 3; ++d3) {
          int d = d3 * 16 + l15;
          if (d < HDIM)
            ctx[(size_t)qr * DIMD + h * HDIM + d] = (__bf16)(o[g][d3][r] * rinv);
        }
      }
    }
  }
}

// ================= kernels =================

__global__ void k_adaln(const float* __restrict__ emb, const float* __restrict__ W,
                        const float* __restrict__ b, float* __restrict__ ada) {
  __shared__ __attribute__((aligned(16))) float se[512];
  int tid = threadIdx.x;
  for (int i = tid; i < 512; i += 64) {
    float e = emb[i];
    se[i] = e / (1.f + __expf(-e));
  }
  __syncthreads();
  int col = blockIdx.x * 64 + tid;
  float acc = 0.f;
  #pragma unroll 8
  for (int k = 0; k < 512; ++k) acc += se[k] * W[(size_t)k * 30720 + col];
  ada[col] = acc + b[col];
}

// lnmod(1248) + qkv_w transpose(4800) fused (guests at dense tail)
__global__ __launch_bounds__(256) void k_lnmod_qtrans(const float* __restrict__ X,
                                                      const float* __restrict__ ada,
                                                      const int* __restrict__ tlp,
                                                      __bf16* __restrict__ Y,
                                                      const float* __restrict__ W,
                                                      __bf16* __restrict__ Wt) {
  __shared__ __attribute__((aligned(16))) char sm[16640];
  int b = blockIdx.x;
  if (b < 1248) dev_lnmod(b, X, ada, 6, 7, 0, 1, tlp, Y, sm);
  else dev_trans(b - 1248, W, Wt, 2560, 7680, sm);
}

// GEMM + weight-transpose fused (gemm blocks first, guests at dense tail)
template <int EPI>
__global__ __launch_bounds__(256) void k_gemm_trans(
    const __bf16* __restrict__ A, int lda, const __bf16* __restrict__ Bt, int ldb,
    const float* __restrict__ bias, int N, int ksize,
    float* __restrict__ Cf, float* __restrict__ Cp, __bf16* __restrict__ Cb,
    unsigned gx, unsigned gy, unsigned gz,
    const float* __restrict__ W, __bf16* __restrict__ Wt, int tK, int tN) {
  __shared__ __attribute__((aligned(16))) char sm[49152];
  int b = blockIdx.x;
  int split = (int)(gx * gy * gz);
  if (b < split) dev_gemm<EPI>(b, gx, gy, gz, A, lda, Bt, ldb, bias, N, ksize, Cf, Cp, Cb, sm);
  else dev_trans(b - split, W, Wt, tK, tN, sm);
}

// plain GEMM
template <int EPI>
__global__ __launch_bounds__(256) void k_gemm(
    const __bf16* __restrict__ A, int lda, const __bf16* __restrict__ Bt, int ldb,
    const float* __restrict__ bias, int N, int ksize,
    float* __restrict__ Cf, float* __restrict__ Cp, __bf16* __restrict__ Cb) {
  __shared__ __attribute__((aligned(16))) char sm[49152];
  int vbid = (blockIdx.z * gridDim.y + blockIdx.y) * gridDim.x + blockIdx.x;
  dev_gemm<EPI>(vbid, gridDim.x, gridDim.y, gridDim.z, A, lda, Bt, ldb, bias, N, ksize,
                Cf, Cp, Cb, sm);
}

// attention(640) + ff1_w transpose(6400) fused (guests at dense tail)
__global__ __launch_bounds__(256) void k_attn_trans(const __bf16* __restrict__ Qb,
                                                    const __bf16* __restrict__ Kb,
                                                    const __bf16* __restrict__ Vt,
                                                    const float* __restrict__ mask,
                                                    __bf16* __restrict__ ctx,
                                                    const float* __restrict__ W,
                                                    __bf16* __restrict__ Wt, int tK, int tN) {
  __shared__ __attribute__((aligned(16))) char sm[49152];
  int b = blockIdx.x;
  if (b < 640) dev_attn(b, Qb, Kb, Vt, mask, ctx, sm);
  else dev_trans(b - 640, W, Wt, tK, tN, sm);
}

// qkv-prep fused: per-head q/k LN (624 blocks, 2 rows each) + V transpose (1280 blocks)
__global__ __launch_bounds__(256) void k_qkvprep(const __bf16* __restrict__ qkv,
                                                 __bf16* __restrict__ Qb,
                                                 __bf16* __restrict__ Kb,
                                                 __bf16* __restrict__ Vt) {
  __shared__ __attribute__((aligned(16))) char sm[40960];
  int b = blockIdx.x, tid = threadIdx.x;
  if (b < 624) {
    float (*buf)[5120] = (float(*)[5120])sm;
    int sub = tid >> 7, t2 = tid & 127;
    int srow = b * 2 + sub;
    const __bf16* rowp = qkv + (size_t)srow * T3;
    for (int i = t2; i < 640; i += 128) {
      bf16x8 v = *(const bf16x8*)&rowp[i * 8];
      #pragma unroll
      for (int j = 0; j < 8; ++j) buf[sub][i * 8 + j] = (float)v[j];
    }
    __syncthreads();
    int h = t2 & 63;
    bool isK = t2 >= 64;
    const float* x = buf[sub] + (isK ? DIMD : 0) + h * HDIM;
    float xv[40], s = 0.f;
    #pragma unroll
    for (int d = 0; d < 40; ++d) { xv[d] = x[d]; s += xv[d]; }
    float mean = s * (1.f / 40.f);
    float s2 = 0.f;
    #pragma unroll
    for (int d = 0; d < 40; ++d) { float t = xv[d] - mean; s2 += t * t; }
    float rstd = rsqrtf(s2 * (1.f / 40.f) + 1e-6f);
    float scale = isK ? rstd : rstd * 0.15811388300841897f;  // 1/sqrt(40) folded into q
    __bf16* dst = (isK ? Kb : Qb) + ((size_t)h * S_PAD + srow) * 64;
    #pragma unroll
    for (int i = 0; i < 5; ++i) {
      bf16x8 w;
      #pragma unroll
      for (int j = 0; j < 8; ++j) w[j] = (__bf16)((xv[i * 8 + j] - mean) * scale);
      *(bf16x8*)&dst[i * 8] = w;
    }
    bf16x8 z = {};
    *(bf16x8*)&dst[40] = z;
    *(bf16x8*)&dst[48] = z;
    *(bf16x8*)&dst[56] = z;
  } else {
    float (*t)[41] = (float(*)[41])sm;
    int vbid = b - 624;
    int h = vbid / 20, s0 = (vbid % 20) * 64;
    for (int i = tid; i < 64 * 40; i += 256) {
      int sr = i / 40, d = i - sr * 40;
      int srow = s0 + sr;
      t[sr][d] = (srow < S_LEN) ? (float)qkv[(size_t)srow * T3 + 2 * DIMD + h * HDIM + d] : 0.f;
    }
    __syncthreads();
    int d = tid >> 2, sc = (tid & 3) * 16;
    bf16x8 w0 = {}, w1 = {};
    if (d < 40) {
      #pragma unroll
      for (int q = 0; q < 8; ++q) {
        w0[q] = (__bf16)t[sc + q][d];
        w1[q] = (__bf16)t[sc + 8 + q][d];
      }
    } else if (d == 40) {
      #pragma unroll
      for (int q = 0; q < 8; ++q) { w0[q] = (__bf16)1.0f; w1[q] = (__bf16)1.0f; }
    }
    __bf16* dst = Vt + ((size_t)h * 64 + d) * S_PAD + s0 + sc;
    *(bf16x8*)&dst[0] = w0;
    *(bf16x8*)&dst[8] = w1;
  }
}

// fused: split-K2 reduce + bias + gated residual -> h (f32), then LN + modulate -> bf16
__global__ __launch_bounds__(256) void k_redln(const float* __restrict__ p0,
                                               const float* __restrict__ p1,
                                               const float* __restrict__ bias,
                                               const float* __restrict__ resid,
                                               const float* __restrict__ ada,
                                               int g_t, int g_i,
                                               int csh_t, int csc_t, int csh_i, int csc_i,
                                               const int* __restrict__ tlp,
                                               float* __restrict__ hout,
                                               __bf16* __restrict__ Y) {
  __shared__ float rs[4], rq[4];
  int row = blockIdx.x, tid = threadIdx.x;
  int txt = *tlp;
  bool isTxt = row < txt;
  size_t off = (size_t)row * DIMD;
  const float* gp = ada + (size_t)(isTxt ? g_t : g_i) * DIMD;
  float v[10], s = 0.f, s2 = 0.f;
  #pragma unroll
  for (int i = 0; i < 10; ++i) {
    int col = tid + i * 256;
    float val = p0[off + col] + p1[off + col] + bias[col];
    float hh = resid[off + col] + gp[col] * val;
    hout[off + col] = hh;
    v[i] = hh; s += hh; s2 += hh * hh;
  }
  #pragma unroll
  for (int m = 1; m < 64; m <<= 1) { s += __shfl_xor(s, m, 64); s2 += __shfl_xor(s2, m, 64); }
  if ((tid & 63) == 0) { rs[tid >> 6] = s; rq[tid >> 6] = s2; }
  __syncthreads();
  s = rs[0] + rs[1] + rs[2] + rs[3];
  s2 = rq[0] + rq[1] + rq[2] + rq[3];
  float mean = s * (1.f / DIMD);
  float rstd = rsqrtf(s2 * (1.f / DIMD) - mean * mean + 1e-6f);
  int csh = isTxt ? csh_t : csh_i, csc = isTxt ? csc_t : csc_i;
  #pragma unroll
  for (int i = 0; i < 10; ++i) {
    int col = tid + i * 256;
    float y = (v[i] - mean) * rstd;
    y = y * (1.f + ada[csc * DIMD + col]) + ada[csh * DIMD + col];
    Y[off + col] = (__bf16)y;
  }
}

// split-K reduce (2 slices) + bias + gated residual (final output)
__global__ __launch_bounds__(256) void k_red2(const float* __restrict__ p0,
                                              const float* __restrict__ p1,
                                              const float* __restrict__ bias,
                                              const float* __restrict__ resid,
                                              const float* __restrict__ ada,
                                              int g_t, int g_i, const int* __restrict__ tlp,
                                              float* __restrict__ out) {
  int idx = blockIdx.x * 256 + threadIdx.x;
  int perRow = DIMD >> 2;
  int row = idx / perRow;
  int c4 = (idx - row * perRow) << 2;
  if (row >= S_LEN) return;
  int txt = *tlp;
  size_t off = (size_t)row * DIMD + c4;
  const float4 a = *(const float4*)&p0[off];
  const float4 p = *(const float4*)&p1[off];
  const float4 bb = *(const float4*)&bias[c4];
  const float4 rr = *(const float4*)&resid[off];
  const float4 gg = *(const float4*)&ada[(size_t)(row < txt ? g_t : g_i) * DIMD + c4];
  float4 o;
  o.x = rr.x + gg.x * (a.x + p.x + bb.x);
  o.y = rr.y + gg.y * (a.y + p.y + bb.y);
  o.z = rr.z + gg.z * (a.z + p.z + bb.z);
  o.w = rr.w + gg.w * (a.w + p.w + bb.w);
  *(float4*)&out[off] = o;
}

extern "C" void kernel_launch(void* const* d_in, const int* in_sizes, int n_in,
                              void* d_out, int out_size, void* d_ws, size_t ws_size,
                              hipStream_t stream) {
  const float* hidden  = (const float*)d_in[0];
  const float* emb     = (const float*)d_in[1];
  const float* mask    = (const float*)d_in[2];
  const float* adaln_w = (const float*)d_in[3];
  const float* adaln_b = (const float*)d_in[4];
  const float* qkv_w   = (const float*)d_in[5];
  const float* qkv_b   = (const float*)d_in[6];
  const float* out_w   = (const float*)d_in[7];
  const float* out_b   = (const float*)d_in[8];
  const float* ff1_w   = (const float*)d_in[9];
  const float* ff1_b   = (const float*)d_in[10];
  const float* ff2_w   = (const float*)d_in[11];
  const float* ff2_b   = (const float*)d_in[12];
  const int*   tl      = (const int*)d_in[13];
  (void)in_sizes; (void)n_in; (void)out_size; (void)ws_size;

  char* w = (char*)d_ws;
  size_t off = 0;
  auto alloc = [&](size_t b) { char* p = w + off; off += (b + 255) & ~(size_t)255; return p; };
  float*  ada  = (float*)alloc(30720 * 4);
  __bf16* wTf1 = (__bf16*)alloc((size_t)10240 * 2560 * 2);       // ff1_w (52.4MB)
  __bf16* wTq2 = (__bf16*)alloc((size_t)10240 * 2560 * 2);       // qkv_w then ff2_w (52.4MB)
  __bf16* ai   = (__bf16*)alloc((size_t)S_PAD * DIMD * 2);       // lnmod out / mi
  __bf16* actB = (__bf16*)alloc((size_t)S_PAD * 10240 * 2);      // qkvB then ff1o (26.2MB)
  __bf16* Qb   = (__bf16*)alloc((size_t)NHEAD * S_PAD * 64 * 2);
  __bf16* Kb   = (__bf16*)alloc((size_t)NHEAD * S_PAD * 64 * 2);
  __bf16* Vt   = (__bf16*)alloc((size_t)NHEAD * 64 * S_PAD * 2);
  __bf16* ctxb = (__bf16*)alloc((size_t)S_PAD * DIMD * 2);
  float*  hbuf = (float*)alloc((size_t)S_PAD * DIMD * 4);        // out_w-trans region, then h
  __bf16* mi    = ai;
  __bf16* qkvB  = actB;
  __bf16* ff1o  = actB;
  __bf16* wTo   = (__bf16*)hbuf;  // out_w bf16 13.1MB, dead before k_redln writes hbuf
  float*  partO = (float*)Qb;     // out-proj partials 2x13.1MB over Qb+Kb+Vt (dead after attn)
  float*  partF = (float*)Qb;     // ff2 partials (same region, dead after redln)

  k_adaln<<<dim3(480), dim3(64), 0, stream>>>(emb, adaln_w, adaln_b, ada);
  // lnmod (1248) || qkv_w transpose (4800)
  k_lnmod_qtrans<<<dim3(1248 + 4800), dim3(256), 0, stream>>>(hidden, ada, tl, ai, qkv_w, wTq2);
  // qkv GEMM (600, bf16 out EPI4) || out_w transpose (1600 -> wTo in hbuf region)
  k_gemm_trans<4><<<dim3(600 + 1600), dim3(256), 0, stream>>>(
      ai, 2560, wTq2, 2560, qkv_b, 7680, 2560, nullptr, nullptr, qkvB,
      10, 60, 1, out_w, wTo, 2560, 2560);
  // q/k LN (624) || V transpose (1280)
  k_qkvprep<<<dim3(624 + 1280), dim3(256), 0, stream>>>(qkvB, Qb, Kb, Vt);
  // attention (640) || ff1_w transpose (6400)
  k_attn_trans<<<dim3(640 + 6400), dim3(256), 0, stream>>>(Qb, Kb, Vt, mask, ctxb,
                                                           ff1_w, wTf1, 2560, 10240);
  // out-proj: plain split-K=2 (400)
  k_gemm<3><<<dim3(10, 20, 2), dim3(256), 0, stream>>>(ctxb, 2560, wTo, 2560, nullptr, 2560, 1280,
                                                       partO, partO + (size_t)S_PAD * 2560, nullptr);
  // fused: reduce+residual -> hbuf, LN+modulate -> mi
  k_redln<<<dim3(1248), dim3(256), 0, stream>>>(partO, partO + (size_t)S_PAD * 2560, out_b,
                                                hidden, ada, 8, 2, 9, 10, 3, 4, tl, hbuf, mi);
  // ff1 GEMM (800, gelu EPI2) || ff2_w transpose (6400 -> wTq2, qkv content dead)
  k_gemm_trans<2><<<dim3(800 + 6400), dim3(256), 0, stream>>>(
      mi, 2560, wTf1, 2560, ff1_b, 10240, 2560, nullptr, nullptr, ff1o,
      10, 80, 1, ff2_w, wTq2, 10240, 2560);
  // ff2: split-K=2 (400 blocks, 80 steps)
  k_gemm<3><<<dim3(10, 20, 2), dim3(256), 0, stream>>>(ff1o, 10240, wTq2, 10240, nullptr, 2560, 5120,
                                                       partF, partF + (size_t)S_PAD * 2560, nullptr);
  k_red2<<<dim3(3120), dim3(256), 0, stream>>>(partF, partF + (size_t)S_PAD * 2560, ff2_b,
                                               hbuf, ada, 11, 5, tl, (float*)d_out);
}